// Round 9
// baseline (456.237 us; speedup 1.0000x reference)
//
#include <hip/hip_runtime.h>
#include <hip/hip_cooperative_groups.h>
#include <math.h>

namespace cg = cooperative_groups;

#define B 256
#define D 512
#define S 196
#define SQ 49      // float4 quads per 196-float row
#define GRID 512   // 2 blocks/CU -- co-resident for cooperative grid sync
#define ROUNDS 4   // 2048 chunks / 512 blocks
#define NINST 49   // 1KB DMA instructions per 64-row chunk (64*784B = 49*1024B)

// Async global->LDS DMA: 16B/lane, 1KB/wave-instruction, no VGPR destination
// (queue depth independent of the register allocator). LDS base wave-uniform.
__device__ __forceinline__ void stage1k(const float* __restrict__ g,
                                        float* lds_base, int lane) {
    __builtin_amdgcn_global_load_lds(
        (const __attribute__((address_space(1))) void*)(g + 4 * lane),
        (__attribute__((address_space(3))) void*)lds_base,
        16, 0, 0);
}

// Single cooperative kernel. Chunk = (b, c): 64 rows of kb[b] (c-th group).
// Per round r: block g owns chunk g + 512*r. kb is read from HBM EXACTLY
// once (DMA->LDS), both the logits pass and the weighted-sum pass consume
// the LDS copy; grid.sync between them publishes the per-chunk rai partials.
// p[b,d] = mem*(u@W)+u (u = ctrl*w_attn; b_concat is softmax-shift-invariant,
// dropped) is recomputed per block from L2-resident W -- removes the gemm
// kernel/phase and overlaps the DMA fill window.
__global__ __launch_bounds__(256) void k_coop(const float* __restrict__ mem,
                                              const float* __restrict__ ctrl,
                                              const float* __restrict__ W,
                                              const float* __restrict__ w_attn,
                                              const float* __restrict__ kb,
                                              float* __restrict__ rai_all,
                                              float* __restrict__ out) {
    __shared__ float kb_s[64 * S];      // 50176 B
    __shared__ float p_s[64];
    __shared__ float part[4][S];        // per-wave logit partials
    __shared__ float rvi_s[S];
    __shared__ float pred[4][64];       // p partial reduce (wave-major)
    __shared__ float redm[4], reds[4];
    cg::grid_group grid = cg::this_grid();

    const int g = blockIdx.x;
    const int t = threadIdx.x;
    const int w = t >> 6, l = t & 63;

    // stage round-0 chunk
    {
        const float* base0 = kb + (size_t)g * 64 * S;
        for (int inst = w; inst < NINST; inst += 4)
            stage1k(base0 + inst * 256, &kb_s[inst * 256], l);
    }

#pragma unroll 1
    for (int r = 0; r < ROUNDS; ++r) {
        const int chunk = g + GRID * r;          // < 2048 always
        const int b = chunk >> 3, c = chunk & 7;

        // ---- p-compute (overlaps the in-flight DMA): wave w covers e-chunk
        // w*128..+128, lane l covers d = c*64+l. W reads are 256B coalesced
        // segments, L2-resident (1 MB). ----
        {
            float acc = 0.f;
            for (int i = 0; i < 128; i += 8) {
                float wv[8], uv[8];
#pragma unroll
                for (int j = 0; j < 8; ++j) {
                    const int e = w * 128 + i + j;
                    wv[j] = W[e * D + c * 64 + l];
                    uv[j] = ctrl[b * D + e] * w_attn[e];
                }
#pragma unroll
                for (int j = 0; j < 8; ++j) acc += uv[j] * wv[j];
            }
            pred[w][l] = acc;
        }
        __syncthreads();
        if (t < 64) {
            const int d = c * 64 + t;
            const float s = (pred[0][t] + pred[1][t]) + (pred[2][t] + pred[3][t]);
            p_s[t] = mem[b * D + d] * s + ctrl[b * D + d] * w_attn[d];
        }
        __syncthreads();   // drains DMA vmcnt(0) too: kb_s now valid

        // ---- logits from LDS: wave w -> rows w*16..+16, lanes 0-48 ----
        if (l < SQ) {
            float4 acc = {0.f, 0.f, 0.f, 0.f};
#pragma unroll
            for (int i = 0; i < 16; ++i) {
                const int row = w * 16 + i;
                const float4 v = *(const float4*)&kb_s[row * S + 4 * l];
                const float pv = p_s[row];
                acc.x += pv * v.x; acc.y += pv * v.y;
                acc.z += pv * v.z; acc.w += pv * v.w;
            }
            *(float4*)&part[w][4 * l] = acc;
        }
        __syncthreads();
        if (t < S)
            rai_all[(size_t)chunk * S + t] =
                (part[0][t] + part[1][t]) + (part[2][t] + part[3][t]);

        // ---- publish partials; all 8 chunks of every batch in this round ----
        grid.sync();

        // ---- softmax (8 L2-hot partials of batch b) ----
        float rai = -INFINITY;
        if (t < S) {
            float v = 0.f;
#pragma unroll
            for (int k = 0; k < 8; ++k)
                v += rai_all[((size_t)b * 8 + k) * S + t];
            rai = v;
        }
        float m = rai;
#pragma unroll
        for (int o = 1; o < 64; o <<= 1) m = fmaxf(m, __shfl_xor(m, o, 64));
        if (l == 0) redm[w] = m;
        __syncthreads();
        m = fmaxf(fmaxf(redm[0], redm[1]), fmaxf(redm[2], redm[3]));
        float ex = (t < S) ? __expf(rai - m) : 0.f;
        float sm = ex;
#pragma unroll
        for (int o = 1; o < 64; o <<= 1) sm += __shfl_xor(sm, o, 64);
        if (l == 0) reds[w] = sm;
        __syncthreads();
        const float li = (reds[0] + reds[1]) + (reds[2] + reds[3]);
        if (t < S) rvi_s[t] = ex / li;
        __syncthreads();

        // ---- weighted sum from the SAME LDS chunk (no kb re-read) ----
        float4 rv = {0.f, 0.f, 0.f, 0.f};
        if (l < SQ) rv = *(const float4*)&rvi_s[4 * l];
#pragma unroll
        for (int i = 0; i < 16; ++i) {
            const int row = w * 16 + i;
            float a = 0.f;
            if (l < SQ) {
                const float4 v = *(const float4*)&kb_s[row * S + 4 * l];
                a = rv.x * v.x + rv.y * v.y + rv.z * v.z + rv.w * v.w;
            }
#pragma unroll
            for (int o = 1; o < 64; o <<= 1) a += __shfl_xor(a, o, 64);
            if (l == 0) out[(size_t)b * D + c * 64 + row] = a;
        }
        __syncthreads();   // all kb_s reads done before DMA overwrites it

        // ---- issue next round's DMA (fills under next p-compute) ----
        if (r + 1 < ROUNDS) {
            const float* basen = kb + (size_t)(chunk + GRID) * 64 * S;
            for (int inst = w; inst < NINST; inst += 4)
                stage1k(basen + inst * 256, &kb_s[inst * 256], l);
        }
    }
}

extern "C" void kernel_launch(void* const* d_in, const int* in_sizes, int n_in,
                              void* d_out, int out_size, void* d_ws, size_t ws_size,
                              hipStream_t stream) {
    const float* mem  = (const float*)d_in[0];  // [B, d]
    const float* ctrl = (const float*)d_in[1];  // [B, d]
    const float* kb   = (const float*)d_in[2];  // [B, d, S]
    const float* W    = (const float*)d_in[3];  // [d, d]
    // d_in[4] = b_concat: softmax-invariant, unused
    const float* wat  = (const float*)d_in[5];  // [d]
    float* out = (float*)d_out;                 // [B, d]
    float* rai_all = (float*)d_ws;              // 2048 * S floats = 1.6 MB

    void* args[] = {(void*)&mem, (void*)&ctrl, (void*)&W, (void*)&wat,
                    (void*)&kb, (void*)&rai_all, (void*)&out};
    hipLaunchCooperativeKernel((const void*)k_coop, dim3(GRID), dim3(256),
                               args, 0, stream);
}